// Round 4
// baseline (163.268 us; speedup 1.0000x reference)
//
#include <hip/hip_runtime.h>

#define LN_EPS 1e-5f

static __device__ __forceinline__ float4 f4zero() { return make_float4(0.f, 0.f, 0.f, 0.f); }

// ---------------------------------------------------------------------------
// K1: feat[N][32] = X[N][128] @ Wf[128][32] + bf ;  skill[N] = (int)X[n][0]
// 8 threads/row. __launch_bounds__(256,8): cap VGPR at 64 -> 32 waves/CU
// (live set ~40 regs: acc4 + 4x w4 + xv4 + addressing). Latency-bound
// kernel: residency is the throughput knob.
// ---------------------------------------------------------------------------
__global__ __launch_bounds__(256, 8) void k_feat(
    const float* __restrict__ X, const float* __restrict__ Wf,
    const float* __restrict__ bf, float* __restrict__ feat,
    int* __restrict__ skill, int N)
{
    __shared__ float Wl[128 * 32];
    for (int i = threadIdx.x; i < 128 * 32; i += 256) Wl[i] = Wf[i];
    __syncthreads();

    const int gid = blockIdx.x * 256 + threadIdx.x;
    const int row = gid >> 3;          // one row per 8 threads
    const int dg  = gid & 7;           // dims 4*dg .. 4*dg+3
    if (row >= N) return;

    const float4* __restrict__ X4 = (const float4*)X + (size_t)row * 32;
    const float4* __restrict__ W4 = (const float4*)Wl;

    float4 acc = *(const float4*)(bf + 4 * dg);

    #pragma unroll 8
    for (int f4 = 0; f4 < 32; ++f4) {
        const float4 xv = X4[f4];
        if (f4 == 0 && dg == 0) skill[row] = (int)xv.x;  // trunc == astype(int32)
        const float4 w0 = W4[(4 * f4 + 0) * 8 + dg];
        const float4 w1 = W4[(4 * f4 + 1) * 8 + dg];
        const float4 w2 = W4[(4 * f4 + 2) * 8 + dg];
        const float4 w3 = W4[(4 * f4 + 3) * 8 + dg];
        acc.x = fmaf(xv.x, w0.x, acc.x);
        acc.y = fmaf(xv.x, w0.y, acc.y);
        acc.z = fmaf(xv.x, w0.z, acc.z);
        acc.w = fmaf(xv.x, w0.w, acc.w);
        acc.x = fmaf(xv.y, w1.x, acc.x);
        acc.y = fmaf(xv.y, w1.y, acc.y);
        acc.z = fmaf(xv.y, w1.z, acc.z);
        acc.w = fmaf(xv.y, w1.w, acc.w);
        acc.x = fmaf(xv.z, w2.x, acc.x);
        acc.y = fmaf(xv.z, w2.y, acc.y);
        acc.z = fmaf(xv.z, w2.z, acc.z);
        acc.w = fmaf(xv.z, w2.w, acc.w);
        acc.x = fmaf(xv.w, w3.x, acc.x);
        acc.y = fmaf(xv.w, w3.y, acc.y);
        acc.z = fmaf(xv.w, w3.z, acc.z);
        acc.w = fmaf(xv.w, w3.w, acc.w);
    }

    *(float4*)(feat + (size_t)row * 32 + 4 * dg) = acc;
}

// ---------------------------------------------------------------------------
// K2a: per-(b,l) row pipeline, 8 threads/row (dg = 4-dim quadrant).
// Low-VGPR rewrite: the hist@Wgcn GEMV interleaves the 8-lane shfl
// broadcast with the FMAs instead of materializing h[32] -- peak live set
// ~50 regs. __launch_bounds__(256,8) caps VGPR at 64 -> 32 waves/CU
// resident (was 16 at ~100 VGPR): 2x TLP for the 40 gather loads/wave.
// ---------------------------------------------------------------------------
__global__ __launch_bounds__(256, 8) void k_rows(
    const float* __restrict__ feat, const int* __restrict__ skill,
    const int* __restrict__ rnodes, const int* __restrict__ ridx,
    const int* __restrict__ dst_ids,
    const float* __restrict__ w_struct, const float* __restrict__ b_struct,
    const float* __restrict__ ln_g, const float* __restrict__ ln_b,
    const float* __restrict__ Wg, float* __restrict__ xw_out, int BL)
{
    __shared__ float Wgl[32 * 32];
    for (int i = threadIdx.x; i < 1024; i += 256) Wgl[i] = Wg[i];
    __syncthreads();

    const int rid = blockIdx.x * 32 + (threadIdx.x >> 3);
    if (rid >= BL) return;
    const int dg   = threadIdx.x & 7;
    const int lane = threadIdx.x & 63;
    const int b = rid / 100;
    const int l = rid - b * 100;

    const int* __restrict__ rb = ridx + b * 5;
    const int cskill = skill[dst_ids[b]];   // same addr across lanes of b: broadcast

    // issue all 5 node-id gathers first (independent), then feat/skill gathers
    int nodes[5];
    #pragma unroll
    for (int r = 0; r < 5; ++r) nodes[r] = rnodes[(size_t)rb[r] * 100 + l];

    float4 acc = f4zero();
    int simc = 0;
    #pragma unroll
    for (int r = 0; r < 5; ++r) {
        simc += (skill[nodes[r]] == cskill) ? 1 : 0;
        const float4 v = *(const float4*)(feat + (size_t)nodes[r] * 32 + 4 * dg);
        acc.x += v.x; acc.y += v.y; acc.z += v.z; acc.w += v.w;
    }

    const float simf = (float)simc * 0.2f;
    {
        const float4 ws = ((const float4*)w_struct)[dg];
        const float4 bs = ((const float4*)b_struct)[dg];
        acc.x = fmaf(acc.x, 0.2f, fmaf(simf, ws.x, bs.x));
        acc.y = fmaf(acc.y, 0.2f, fmaf(simf, ws.y, bs.y));
        acc.z = fmaf(acc.z, 0.2f, fmaf(simf, ws.z, bs.z));
        acc.w = fmaf(acc.w, 0.2f, fmaf(simf, ws.w, bs.w));
    }

    // LayerNorm over D=32 = 8 lanes x 4 dims (two-pass, biased var)
    float part = acc.x + acc.y + acc.z + acc.w;
    part += __shfl_xor(part, 1);
    part += __shfl_xor(part, 2);
    part += __shfl_xor(part, 4);
    const float mu = part * (1.f / 32.f);
    float dx, sq;
    dx = acc.x - mu; sq  = dx * dx;
    dx = acc.y - mu; sq  = fmaf(dx, dx, sq);
    dx = acc.z - mu; sq  = fmaf(dx, dx, sq);
    dx = acc.w - mu; sq  = fmaf(dx, dx, sq);
    sq += __shfl_xor(sq, 1);
    sq += __shfl_xor(sq, 2);
    sq += __shfl_xor(sq, 4);
    const float rs = rsqrtf(sq * (1.f / 32.f) + LN_EPS);

    float4 y;
    {
        const float4 g4 = ((const float4*)ln_g)[dg];
        const float4 b4 = ((const float4*)ln_b)[dg];
        y.x = fmaf((acc.x - mu) * rs, g4.x, b4.x);
        y.y = fmaf((acc.y - mu) * rs, g4.y, b4.y);
        y.z = fmaf((acc.z - mu) * rs, g4.z, b4.z);
        y.w = fmaf((acc.w - mu) * rs, g4.w, b4.w);
    }

    // xw quadrant: xw[4dg+j] = sum_k h[k]*Wg[k][4dg+j], h broadcast lazily
    // from the 8-lane group (4 shfl temps live at a time, no h[32] array).
    float4 o = f4zero();
    const float4* __restrict__ W4 = (const float4*)Wgl;
    const int base = lane & ~7;
    #pragma unroll
    for (int s = 0; s < 8; ++s) {
        const float hx = __shfl(y.x, base + s, 64);
        const float hy = __shfl(y.y, base + s, 64);
        const float hz = __shfl(y.z, base + s, 64);
        const float hw = __shfl(y.w, base + s, 64);
        const float4 w0 = W4[(4 * s + 0) * 8 + dg];
        const float4 w1 = W4[(4 * s + 1) * 8 + dg];
        const float4 w2 = W4[(4 * s + 2) * 8 + dg];
        const float4 w3 = W4[(4 * s + 3) * 8 + dg];
        o.x = fmaf(hx, w0.x, o.x);
        o.y = fmaf(hx, w0.y, o.y);
        o.z = fmaf(hx, w0.z, o.z);
        o.w = fmaf(hx, w0.w, o.w);
        o.x = fmaf(hy, w1.x, o.x);
        o.y = fmaf(hy, w1.y, o.y);
        o.z = fmaf(hy, w1.z, o.z);
        o.w = fmaf(hy, w1.w, o.w);
        o.x = fmaf(hz, w2.x, o.x);
        o.y = fmaf(hz, w2.y, o.y);
        o.z = fmaf(hz, w2.z, o.z);
        o.w = fmaf(hz, w2.w, o.w);
        o.x = fmaf(hw, w3.x, o.x);
        o.y = fmaf(hw, w3.y, o.y);
        o.z = fmaf(hw, w3.z, o.z);
        o.w = fmaf(hw, w3.w, o.w);
    }

    *(float4*)(xw_out + (size_t)rid * 32 + 4 * dg) = o;
}

// ---------------------------------------------------------------------------
// K2b: per-sample tail. 1024 blocks x 128 threads. xwT padded to [32][101]:
// write/read banks 2-way (free, m136), pool reads (5t+j)%32 conflict-free.
// ---------------------------------------------------------------------------
__global__ __launch_bounds__(128) void k_tail(
    const float* __restrict__ feat, const int* __restrict__ rnodes,
    const int* __restrict__ ridx, const int* __restrict__ dst_ids,
    const float* __restrict__ xw_in, const float* __restrict__ b_gcn,
    const float* __restrict__ Wo, const float* __restrict__ b_out,
    float* __restrict__ out, int B)
{
    __shared__ float Wol[32 * 32];
    __shared__ float xwT[32][101];
    __shared__ float pooled[32];
    __shared__ int   pidx0;

    const int t = threadIdx.x, b = blockIdx.x;

    for (int i = t; i < 1024; i += 128) Wol[i] = Wo[i];
    if (t == 0) pidx0 = ridx[b * 5];
    __syncthreads();

    const int l = t;
    const int node0 = (l < 100) ? rnodes[(size_t)pidx0 * 100 + l] : 0;
    const int valid = __syncthreads_count(node0 > 0);

    float4 xw[8];
    if (l < 100) {
        const float4* xp = (const float4*)(xw_in + ((size_t)b * 100 + l) * 32);
        #pragma unroll
        for (int q = 0; q < 8; ++q) {
            xw[q] = xp[q];
            xwT[4 * q + 0][l] = xw[q].x;
            xwT[4 * q + 1][l] = xw[q].y;
            xwT[4 * q + 2][l] = xw[q].z;
            xwT[4 * q + 3][l] = xw[q].w;
        }
    }
    __syncthreads();

    // chain-GCN: out[l] = xw[l]/deg[l] + edge(l-1->l)*xw[l-1]*rsqrt(deg[l-1]deg[l]);
    // gnn = relu(out + b_gcn). deg[0]=1; deg[v>=1] = 1 + (v < valid).
    if (l < 100) {
        const bool hm = (l >= 1) && (l < valid);
        const float degl  = 1.f + ((l >= 1 && l < valid) ? 1.f : 0.f);
        const float deglm = 1.f + ((l - 1 >= 1 && (l - 1) < valid) ? 1.f : 0.f);
        const float invd  = 1.f / degl;                    // deg in {1,2}: exact
        const float invn  = hm ? rsqrtf(deglm * degl) : 0.f;
        const int lm = hm ? (l - 1) : l;                   // safe LDS index when !hm
        #define GNN_D(D, C) { \
            const float m = hm ? xwT[D][lm] * invn : 0.f; \
            const float o = fmaf(xw[(D) / 4].C, invd, m) + bg4.C; \
            xw[(D) / 4].C = fmaxf(o, 0.f); }
        #pragma unroll
        for (int q = 0; q < 8; ++q) {
            const float4 bg4 = ((const float4*)b_gcn)[q];
            GNN_D(4 * q + 0, x) GNN_D(4 * q + 1, y)
            GNN_D(4 * q + 2, z) GNN_D(4 * q + 3, w)
        }
        #undef GNN_D
    }
    __syncthreads();   // all xwT reads done before overwrite (WAR)

    if (l < 100) {
        #pragma unroll
        for (int q = 0; q < 8; ++q) {
            xwT[4 * q + 0][l] = xw[q].x;
            xwT[4 * q + 1][l] = xw[q].y;
            xwT[4 * q + 2][l] = xw[q].z;
            xwT[4 * q + 3][l] = xw[q].w;
        }
    }
    __syncthreads();

    // global_mean_pool over L=100 (column sums)
    if (t < 32) {
        float s = 0.f;
        for (int j = 0; j < 100; ++j) s += xwT[t][j];
        pooled[t] = s * 0.01f;
    }
    __syncthreads();

    if (t < 32) {
        float s = b_out[t];
        #pragma unroll 8
        for (int k = 0; k < 32; ++k) s = fmaf(pooled[k], Wol[k * 32 + t], s);
        out[(size_t)b * 32 + t] = s;                       // src_emb
    } else if (t < 64) {
        const int d = t - 32;
        const float* fr = feat + (size_t)dst_ids[b] * 32;  // broadcast reads
        float s = b_out[d];
        #pragma unroll 8
        for (int k = 0; k < 32; ++k) s = fmaf(fr[k], Wol[k * 32 + d], s);
        out[(size_t)B * 32 + (size_t)b * 32 + d] = s;      // dst_emb
    }
}

// ---------------------------------------------------------------------------
extern "C" void kernel_launch(void* const* d_in, const int* in_sizes, int n_in,
                              void* d_out, int out_size, void* d_ws, size_t ws_size,
                              hipStream_t stream)
{
    const float* X      = (const float*)d_in[0];   // [N,128]
    const int*   rnodes = (const int*)  d_in[1];   // [P,100]
    const int*   ridx   = (const int*)  d_in[2];   // [B,5]
    /* d_in[3] src_node_ids: unused by reference */
    const int*   dst    = (const int*)  d_in[4];   // [B]
    /* d_in[5] node_interact_times: unused */
    const float* Wf  = (const float*)d_in[6];
    const float* bf  = (const float*)d_in[7];
    const float* wst = (const float*)d_in[8];
    const float* bst = (const float*)d_in[9];
    const float* lg  = (const float*)d_in[10];
    const float* lb  = (const float*)d_in[11];
    const float* Wg  = (const float*)d_in[12];
    const float* bg  = (const float*)d_in[13];
    const float* Wo  = (const float*)d_in[14];
    const float* bo  = (const float*)d_in[15];

    const int N = in_sizes[0] / 128;   // 100000
    const int B = in_sizes[4];         // 1024
    const int BL = B * 100;

    // workspace layout (all 16B-aligned):
    //   feat_all [N,32] f32 | skill [N] i32 (rounded to 16B) | xw [B*L,32] f32
    float* feat  = (float*)d_ws;
    int*   skill = (int*)((char*)d_ws + (size_t)N * 32 * sizeof(float));
    size_t skill_bytes = (((size_t)N * sizeof(int)) + 15) & ~(size_t)15;
    float* xw_ws = (float*)((char*)skill + skill_bytes);
    float* out   = (float*)d_out;

    k_feat<<<(N * 8 + 255) / 256, 256, 0, stream>>>(X, Wf, bf, feat, skill, N);
    k_rows<<<(BL * 8 + 255) / 256, 256, 0, stream>>>(feat, skill, rnodes, ridx, dst,
                                                     wst, bst, lg, lb, Wg, xw_ws, BL);
    k_tail<<<B, 128, 0, stream>>>(feat, rnodes, ridx, dst, xw_ws,
                                  bg, Wo, bo, out, B);
}

// Round 5
// 160.558 us; speedup vs baseline: 1.0169x; 1.0169x over previous
//
#include <hip/hip_runtime.h>

#define LN_EPS 1e-5f

static __device__ __forceinline__ float4 f4zero() { return make_float4(0.f, 0.f, 0.f, 0.f); }

// ---------------------------------------------------------------------------
// K1: feat[N][32] = X[N][128] @ Wf[128][32] + bf ;  skill[N] = (int)X[n][0]
// (unchanged from verified round-4 version)
// ---------------------------------------------------------------------------
__global__ __launch_bounds__(256, 8) void k_feat(
    const float* __restrict__ X, const float* __restrict__ Wf,
    const float* __restrict__ bf, float* __restrict__ feat,
    int* __restrict__ skill, int N)
{
    __shared__ float Wl[128 * 32];
    for (int i = threadIdx.x; i < 128 * 32; i += 256) Wl[i] = Wf[i];
    __syncthreads();

    const int gid = blockIdx.x * 256 + threadIdx.x;
    const int row = gid >> 3;          // one row per 8 threads
    const int dg  = gid & 7;           // dims 4*dg .. 4*dg+3
    if (row >= N) return;

    const float4* __restrict__ X4 = (const float4*)X + (size_t)row * 32;
    const float4* __restrict__ W4 = (const float4*)Wl;

    float4 acc = *(const float4*)(bf + 4 * dg);

    #pragma unroll 8
    for (int f4 = 0; f4 < 32; ++f4) {
        const float4 xv = X4[f4];
        if (f4 == 0 && dg == 0) skill[row] = (int)xv.x;  // trunc == astype(int32)
        const float4 w0 = W4[(4 * f4 + 0) * 8 + dg];
        const float4 w1 = W4[(4 * f4 + 1) * 8 + dg];
        const float4 w2 = W4[(4 * f4 + 2) * 8 + dg];
        const float4 w3 = W4[(4 * f4 + 3) * 8 + dg];
        acc.x = fmaf(xv.x, w0.x, acc.x);
        acc.y = fmaf(xv.x, w0.y, acc.y);
        acc.z = fmaf(xv.x, w0.z, acc.z);
        acc.w = fmaf(xv.x, w0.w, acc.w);
        acc.x = fmaf(xv.y, w1.x, acc.x);
        acc.y = fmaf(xv.y, w1.y, acc.y);
        acc.z = fmaf(xv.y, w1.z, acc.z);
        acc.w = fmaf(xv.y, w1.w, acc.w);
        acc.x = fmaf(xv.z, w2.x, acc.x);
        acc.y = fmaf(xv.z, w2.y, acc.y);
        acc.z = fmaf(xv.z, w2.z, acc.z);
        acc.w = fmaf(xv.z, w2.w, acc.w);
        acc.x = fmaf(xv.w, w3.x, acc.x);
        acc.y = fmaf(xv.w, w3.y, acc.y);
        acc.z = fmaf(xv.w, w3.z, acc.z);
        acc.w = fmaf(xv.w, w3.w, acc.w);
    }

    *(float4*)(feat + (size_t)row * 32 + 4 * dg) = acc;
}

// ---------------------------------------------------------------------------
// K2: fully fused per-sample pipeline, one block per b, 1024 threads
// (16 waves; 2 blocks/CU resident = 32 waves/CU). Threads t = l*8+dg:
// 8-thread group per (b,l) row exactly as the verified k_rows (gathers,
// struct-sim, shfl LayerNorm, lazy-broadcast GEMV) -- but xw stays in LDS
// (xwT[32][101], 2-way-max banks = free) and the verified k_tail phases
// (chain-GCN, pool, output GEMVs) run in the same block. Saves the 26 MB
// xw global roundtrip + one kernel launch. __syncthreads_count doubles as
// the weights barrier.
// ---------------------------------------------------------------------------
__global__ __launch_bounds__(1024, 8) void k_fused(
    const float* __restrict__ feat, const int* __restrict__ skill,
    const int* __restrict__ rnodes, const int* __restrict__ ridx,
    const int* __restrict__ dst_ids,
    const float* __restrict__ w_struct, const float* __restrict__ b_struct,
    const float* __restrict__ ln_g, const float* __restrict__ ln_b,
    const float* __restrict__ Wg, const float* __restrict__ b_gcn,
    const float* __restrict__ Wo, const float* __restrict__ b_out,
    float* __restrict__ out, int B)
{
    __shared__ float Wgl[32 * 32];
    __shared__ float Wol[32 * 32];
    __shared__ float xwT[32][101];
    __shared__ float pooled[32];

    const int t = threadIdx.x, b = blockIdx.x;

    Wgl[t & 1023] = Wg[t & 1023];      // blockDim == 1024: one element each
    Wol[t & 1023] = Wo[t & 1023];

    const int l    = t >> 3;
    const int dg   = t & 7;
    const int lane = t & 63;
    const bool act = (l < 100);

    const int* __restrict__ rb = ridx + b * 5;
    const int cskill = skill[dst_ids[b]];   // same addr across block: broadcast

    int   n0 = 0;
    int   simc = 0;
    float4 acc = f4zero();

    if (act) {
        int nodes[5];
        #pragma unroll
        for (int r = 0; r < 5; ++r) nodes[r] = rnodes[(size_t)rb[r] * 100 + l];
        n0 = nodes[0];
        #pragma unroll
        for (int r = 0; r < 5; ++r) {
            simc += (skill[nodes[r]] == cskill) ? 1 : 0;
            const float4 v = *(const float4*)(feat + (size_t)nodes[r] * 32 + 4 * dg);
            acc.x += v.x; acc.y += v.y; acc.z += v.z; acc.w += v.w;
        }
    }

    // barrier (covers Wgl/Wol staging) + per-b valid count in one op
    const int valid = __syncthreads_count(act && dg == 0 && n0 > 0);

    float4 o = f4zero();
    if (act) {
        const float simf = (float)simc * 0.2f;
        {
            const float4 ws = ((const float4*)w_struct)[dg];
            const float4 bs = ((const float4*)b_struct)[dg];
            acc.x = fmaf(acc.x, 0.2f, fmaf(simf, ws.x, bs.x));
            acc.y = fmaf(acc.y, 0.2f, fmaf(simf, ws.y, bs.y));
            acc.z = fmaf(acc.z, 0.2f, fmaf(simf, ws.z, bs.z));
            acc.w = fmaf(acc.w, 0.2f, fmaf(simf, ws.w, bs.w));
        }

        // LayerNorm over D=32 = 8 lanes x 4 dims (two-pass, biased var)
        float part = acc.x + acc.y + acc.z + acc.w;
        part += __shfl_xor(part, 1);
        part += __shfl_xor(part, 2);
        part += __shfl_xor(part, 4);
        const float mu = part * (1.f / 32.f);
        float dx, sq;
        dx = acc.x - mu; sq  = dx * dx;
        dx = acc.y - mu; sq  = fmaf(dx, dx, sq);
        dx = acc.z - mu; sq  = fmaf(dx, dx, sq);
        dx = acc.w - mu; sq  = fmaf(dx, dx, sq);
        sq += __shfl_xor(sq, 1);
        sq += __shfl_xor(sq, 2);
        sq += __shfl_xor(sq, 4);
        const float rs = rsqrtf(sq * (1.f / 32.f) + LN_EPS);

        float4 y;
        {
            const float4 g4 = ((const float4*)ln_g)[dg];
            const float4 b4 = ((const float4*)ln_b)[dg];
            y.x = fmaf((acc.x - mu) * rs, g4.x, b4.x);
            y.y = fmaf((acc.y - mu) * rs, g4.y, b4.y);
            y.z = fmaf((acc.z - mu) * rs, g4.z, b4.z);
            y.w = fmaf((acc.w - mu) * rs, g4.w, b4.w);
        }

        // xw quadrant: xw[4dg+j] = sum_k h[k]*Wg[k][4dg+j], h broadcast
        // lazily from the 8-lane group (no h[32] array).
        const float4* __restrict__ W4 = (const float4*)Wgl;
        const int base = lane & ~7;
        #pragma unroll
        for (int s = 0; s < 8; ++s) {
            const float hx = __shfl(y.x, base + s, 64);
            const float hy = __shfl(y.y, base + s, 64);
            const float hz = __shfl(y.z, base + s, 64);
            const float hw = __shfl(y.w, base + s, 64);
            const float4 w0 = W4[(4 * s + 0) * 8 + dg];
            const float4 w1 = W4[(4 * s + 1) * 8 + dg];
            const float4 w2 = W4[(4 * s + 2) * 8 + dg];
            const float4 w3 = W4[(4 * s + 3) * 8 + dg];
            o.x = fmaf(hx, w0.x, o.x);
            o.y = fmaf(hx, w0.y, o.y);
            o.z = fmaf(hx, w0.z, o.z);
            o.w = fmaf(hx, w0.w, o.w);
            o.x = fmaf(hy, w1.x, o.x);
            o.y = fmaf(hy, w1.y, o.y);
            o.z = fmaf(hy, w1.z, o.z);
            o.w = fmaf(hy, w1.w, o.w);
            o.x = fmaf(hz, w2.x, o.x);
            o.y = fmaf(hz, w2.y, o.y);
            o.z = fmaf(hz, w2.z, o.z);
            o.w = fmaf(hz, w2.w, o.w);
            o.x = fmaf(hw, w3.x, o.x);
            o.y = fmaf(hw, w3.y, o.y);
            o.z = fmaf(hw, w3.z, o.z);
            o.w = fmaf(hw, w3.w, o.w);
        }

        // publish xw quadrant to LDS (banks 2-way max: free)
        xwT[4 * dg + 0][l] = o.x;
        xwT[4 * dg + 1][l] = o.y;
        xwT[4 * dg + 2][l] = o.z;
        xwT[4 * dg + 3][l] = o.w;
    }
    __syncthreads();

    // chain-GCN: out[l] = xw[l]/deg[l] + edge(l-1->l)*xw[l-1]*rsqrt(deg[l-1]deg[l]);
    // gnn = relu(out + b_gcn). deg[0]=1; deg[v>=1] = 1 + (v < valid).
    if (act) {
        const bool hm = (l >= 1) && (l < valid);
        const float degl  = 1.f + ((l >= 1 && l < valid) ? 1.f : 0.f);
        const float deglm = 1.f + ((l - 1 >= 1 && (l - 1) < valid) ? 1.f : 0.f);
        const float invd  = 1.f / degl;                    // deg in {1,2}: exact
        const float invn  = hm ? rsqrtf(deglm * degl) : 0.f;
        const int lm = hm ? (l - 1) : l;                   // safe LDS index when !hm
        const float4 bg4 = ((const float4*)b_gcn)[dg];
        float m;
        m = hm ? xwT[4 * dg + 0][lm] * invn : 0.f;
        o.x = fmaxf(fmaf(o.x, invd, m) + bg4.x, 0.f);
        m = hm ? xwT[4 * dg + 1][lm] * invn : 0.f;
        o.y = fmaxf(fmaf(o.y, invd, m) + bg4.y, 0.f);
        m = hm ? xwT[4 * dg + 2][lm] * invn : 0.f;
        o.z = fmaxf(fmaf(o.z, invd, m) + bg4.z, 0.f);
        m = hm ? xwT[4 * dg + 3][lm] * invn : 0.f;
        o.w = fmaxf(fmaf(o.w, invd, m) + bg4.w, 0.f);
    }
    __syncthreads();   // all xwT reads done before overwrite (WAR)

    if (act) {
        xwT[4 * dg + 0][l] = o.x;
        xwT[4 * dg + 1][l] = o.y;
        xwT[4 * dg + 2][l] = o.z;
        xwT[4 * dg + 3][l] = o.w;
    }
    __syncthreads();

    // global_mean_pool over L=100 (32 lanes, reads (5t+j)%32: conflict-free)
    if (t < 32) {
        float s = 0.f;
        for (int j = 0; j < 100; ++j) s += xwT[t][j];
        pooled[t] = s * 0.01f;
    }
    __syncthreads();

    if (t < 32) {
        float s = b_out[t];
        #pragma unroll 8
        for (int k = 0; k < 32; ++k) s = fmaf(pooled[k], Wol[k * 32 + t], s);
        out[(size_t)b * 32 + t] = s;                       // src_emb
    } else if (t < 64) {
        const int d = t - 32;
        const float* fr = feat + (size_t)dst_ids[b] * 32;  // broadcast reads
        float s = b_out[d];
        #pragma unroll 8
        for (int k = 0; k < 32; ++k) s = fmaf(fr[k], Wol[k * 32 + d], s);
        out[(size_t)B * 32 + (size_t)b * 32 + d] = s;      // dst_emb
    }
}

// ---------------------------------------------------------------------------
extern "C" void kernel_launch(void* const* d_in, const int* in_sizes, int n_in,
                              void* d_out, int out_size, void* d_ws, size_t ws_size,
                              hipStream_t stream)
{
    const float* X      = (const float*)d_in[0];   // [N,128]
    const int*   rnodes = (const int*)  d_in[1];   // [P,100]
    const int*   ridx   = (const int*)  d_in[2];   // [B,5]
    /* d_in[3] src_node_ids: unused by reference */
    const int*   dst    = (const int*)  d_in[4];   // [B]
    /* d_in[5] node_interact_times: unused */
    const float* Wf  = (const float*)d_in[6];
    const float* bf  = (const float*)d_in[7];
    const float* wst = (const float*)d_in[8];
    const float* bst = (const float*)d_in[9];
    const float* lg  = (const float*)d_in[10];
    const float* lb  = (const float*)d_in[11];
    const float* Wg  = (const float*)d_in[12];
    const float* bg  = (const float*)d_in[13];
    const float* Wo  = (const float*)d_in[14];
    const float* bo  = (const float*)d_in[15];

    const int N = in_sizes[0] / 128;   // 100000
    const int B = in_sizes[4];         // 1024

    // workspace: feat_all [N,32] f32 | skill [N] i32
    float* feat  = (float*)d_ws;
    int*   skill = (int*)((char*)d_ws + (size_t)N * 32 * sizeof(float));
    float* out   = (float*)d_out;

    k_feat<<<(N * 8 + 255) / 256, 256, 0, stream>>>(X, Wf, bf, feat, skill, N);
    k_fused<<<B, 1024, 0, stream>>>(feat, skill, rnodes, ridx, dst,
                                    wst, bst, lg, lb, Wg, bg, Wo, bo, out, B);
}

// Round 6
// 159.915 us; speedup vs baseline: 1.0210x; 1.0040x over previous
//
#include <hip/hip_runtime.h>
#include <hip/hip_fp16.h>

#define LN_EPS 1e-5f

static __device__ __forceinline__ float4 f4zero() { return make_float4(0.f, 0.f, 0.f, 0.f); }

// ---------------------------------------------------------------------------
// K1: feat[N][32](fp16) = X[N][128] @ Wf[128][32] + bf ; skill[N] = (int)X[n][0]
// Same verified structure as R4/R5; only the feat store is now fp16 (rn).
// fp16 feat halves k_feat's write AND k_fused's gather footprint (12.8->6.4MB:
// near-resident in the 4MiB per-XCD L2, ~2x less L2-miss refill traffic).
// ---------------------------------------------------------------------------
__global__ __launch_bounds__(256, 8) void k_feat(
    const float* __restrict__ X, const float* __restrict__ Wf,
    const float* __restrict__ bf, __half* __restrict__ feat,
    int* __restrict__ skill, int N)
{
    __shared__ float Wl[128 * 32];
    for (int i = threadIdx.x; i < 128 * 32; i += 256) Wl[i] = Wf[i];
    __syncthreads();

    const int gid = blockIdx.x * 256 + threadIdx.x;
    const int row = gid >> 3;          // one row per 8 threads
    const int dg  = gid & 7;           // dims 4*dg .. 4*dg+3
    if (row >= N) return;

    const float4* __restrict__ X4 = (const float4*)X + (size_t)row * 32;
    const float4* __restrict__ W4 = (const float4*)Wl;

    float4 acc = *(const float4*)(bf + 4 * dg);

    #pragma unroll 8
    for (int f4 = 0; f4 < 32; ++f4) {
        const float4 xv = X4[f4];
        if (f4 == 0 && dg == 0) skill[row] = (int)xv.x;  // trunc == astype(int32)
        const float4 w0 = W4[(4 * f4 + 0) * 8 + dg];
        const float4 w1 = W4[(4 * f4 + 1) * 8 + dg];
        const float4 w2 = W4[(4 * f4 + 2) * 8 + dg];
        const float4 w3 = W4[(4 * f4 + 3) * 8 + dg];
        acc.x = fmaf(xv.x, w0.x, acc.x);
        acc.y = fmaf(xv.x, w0.y, acc.y);
        acc.z = fmaf(xv.x, w0.z, acc.z);
        acc.w = fmaf(xv.x, w0.w, acc.w);
        acc.x = fmaf(xv.y, w1.x, acc.x);
        acc.y = fmaf(xv.y, w1.y, acc.y);
        acc.z = fmaf(xv.y, w1.z, acc.z);
        acc.w = fmaf(xv.y, w1.w, acc.w);
        acc.x = fmaf(xv.z, w2.x, acc.x);
        acc.y = fmaf(xv.z, w2.y, acc.y);
        acc.z = fmaf(xv.z, w2.z, acc.z);
        acc.w = fmaf(xv.z, w2.w, acc.w);
        acc.x = fmaf(xv.w, w3.x, acc.x);
        acc.y = fmaf(xv.w, w3.y, acc.y);
        acc.z = fmaf(xv.w, w3.z, acc.z);
        acc.w = fmaf(xv.w, w3.w, acc.w);
    }

    union { __half2 h2[2]; uint2 u; } cv;
    cv.h2[0] = __float22half2_rn(make_float2(acc.x, acc.y));
    cv.h2[1] = __float22half2_rn(make_float2(acc.z, acc.w));
    *(uint2*)(feat + (size_t)row * 32 + 4 * dg) = cv.u;   // 8B aligned
}

// ---------------------------------------------------------------------------
// K2: fully fused per-sample pipeline (verified R5 structure), feat now fp16.
// One block per b, 1024 threads (16 waves; 2 blocks/CU = 32 waves/CU).
// 8-thread group per (b,l) row: gathers (now 8B/quadrant), struct-sim,
// shfl LayerNorm, lazy-broadcast GEMV; xw stays in LDS (xwT[32][101]);
// chain-GCN, pool, output GEMVs in the same block.
// ---------------------------------------------------------------------------
__global__ __launch_bounds__(1024, 8) void k_fused(
    const __half* __restrict__ feat, const int* __restrict__ skill,
    const int* __restrict__ rnodes, const int* __restrict__ ridx,
    const int* __restrict__ dst_ids,
    const float* __restrict__ w_struct, const float* __restrict__ b_struct,
    const float* __restrict__ ln_g, const float* __restrict__ ln_b,
    const float* __restrict__ Wg, const float* __restrict__ b_gcn,
    const float* __restrict__ Wo, const float* __restrict__ b_out,
    float* __restrict__ out, int B)
{
    __shared__ float Wgl[32 * 32];
    __shared__ float Wol[32 * 32];
    __shared__ float xwT[32][101];
    __shared__ float pooled[32];

    const int t = threadIdx.x, b = blockIdx.x;

    Wgl[t & 1023] = Wg[t & 1023];      // blockDim == 1024: one element each
    Wol[t & 1023] = Wo[t & 1023];

    const int l    = t >> 3;
    const int dg   = t & 7;
    const int lane = t & 63;
    const bool act = (l < 100);

    const int* __restrict__ rb = ridx + b * 5;
    const int cskill = skill[dst_ids[b]];   // same addr across block: broadcast

    int   n0 = 0;
    int   simc = 0;
    float4 acc = f4zero();

    if (act) {
        int nodes[5];
        #pragma unroll
        for (int r = 0; r < 5; ++r) nodes[r] = rnodes[(size_t)rb[r] * 100 + l];
        n0 = nodes[0];
        #pragma unroll
        for (int r = 0; r < 5; ++r) {
            simc += (skill[nodes[r]] == cskill) ? 1 : 0;
            const uint2 raw = *(const uint2*)(feat + (size_t)nodes[r] * 32 + 4 * dg);
            const float2 f01 = __half22float2(*(const __half2*)&raw.x);
            const float2 f23 = __half22float2(*(const __half2*)&raw.y);
            acc.x += f01.x; acc.y += f01.y; acc.z += f23.x; acc.w += f23.y;
        }
    }

    // barrier (covers Wgl/Wol staging) + per-b valid count in one op
    const int valid = __syncthreads_count(act && dg == 0 && n0 > 0);

    float4 o = f4zero();
    if (act) {
        const float simf = (float)simc * 0.2f;
        {
            const float4 ws = ((const float4*)w_struct)[dg];
            const float4 bs = ((const float4*)b_struct)[dg];
            acc.x = fmaf(acc.x, 0.2f, fmaf(simf, ws.x, bs.x));
            acc.y = fmaf(acc.y, 0.2f, fmaf(simf, ws.y, bs.y));
            acc.z = fmaf(acc.z, 0.2f, fmaf(simf, ws.z, bs.z));
            acc.w = fmaf(acc.w, 0.2f, fmaf(simf, ws.w, bs.w));
        }

        // LayerNorm over D=32 = 8 lanes x 4 dims (two-pass, biased var)
        float part = acc.x + acc.y + acc.z + acc.w;
        part += __shfl_xor(part, 1);
        part += __shfl_xor(part, 2);
        part += __shfl_xor(part, 4);
        const float mu = part * (1.f / 32.f);
        float dx, sq;
        dx = acc.x - mu; sq  = dx * dx;
        dx = acc.y - mu; sq  = fmaf(dx, dx, sq);
        dx = acc.z - mu; sq  = fmaf(dx, dx, sq);
        dx = acc.w - mu; sq  = fmaf(dx, dx, sq);
        sq += __shfl_xor(sq, 1);
        sq += __shfl_xor(sq, 2);
        sq += __shfl_xor(sq, 4);
        const float rs = rsqrtf(sq * (1.f / 32.f) + LN_EPS);

        float4 y;
        {
            const float4 g4 = ((const float4*)ln_g)[dg];
            const float4 b4 = ((const float4*)ln_b)[dg];
            y.x = fmaf((acc.x - mu) * rs, g4.x, b4.x);
            y.y = fmaf((acc.y - mu) * rs, g4.y, b4.y);
            y.z = fmaf((acc.z - mu) * rs, g4.z, b4.z);
            y.w = fmaf((acc.w - mu) * rs, g4.w, b4.w);
        }

        // xw quadrant: xw[4dg+j] = sum_k h[k]*Wg[k][4dg+j], h broadcast
        // lazily from the 8-lane group (no h[32] array).
        const float4* __restrict__ W4 = (const float4*)Wgl;
        const int base = lane & ~7;
        #pragma unroll
        for (int s = 0; s < 8; ++s) {
            const float hx = __shfl(y.x, base + s, 64);
            const float hy = __shfl(y.y, base + s, 64);
            const float hz = __shfl(y.z, base + s, 64);
            const float hw = __shfl(y.w, base + s, 64);
            const float4 w0 = W4[(4 * s + 0) * 8 + dg];
            const float4 w1 = W4[(4 * s + 1) * 8 + dg];
            const float4 w2 = W4[(4 * s + 2) * 8 + dg];
            const float4 w3 = W4[(4 * s + 3) * 8 + dg];
            o.x = fmaf(hx, w0.x, o.x);
            o.y = fmaf(hx, w0.y, o.y);
            o.z = fmaf(hx, w0.z, o.z);
            o.w = fmaf(hx, w0.w, o.w);
            o.x = fmaf(hy, w1.x, o.x);
            o.y = fmaf(hy, w1.y, o.y);
            o.z = fmaf(hy, w1.z, o.z);
            o.w = fmaf(hy, w1.w, o.w);
            o.x = fmaf(hz, w2.x, o.x);
            o.y = fmaf(hz, w2.y, o.y);
            o.z = fmaf(hz, w2.z, o.z);
            o.w = fmaf(hz, w2.w, o.w);
            o.x = fmaf(hw, w3.x, o.x);
            o.y = fmaf(hw, w3.y, o.y);
            o.z = fmaf(hw, w3.z, o.z);
            o.w = fmaf(hw, w3.w, o.w);
        }

        // publish xw quadrant to LDS (banks 2-way max: free)
        xwT[4 * dg + 0][l] = o.x;
        xwT[4 * dg + 1][l] = o.y;
        xwT[4 * dg + 2][l] = o.z;
        xwT[4 * dg + 3][l] = o.w;
    }
    __syncthreads();

    // chain-GCN: out[l] = xw[l]/deg[l] + edge(l-1->l)*xw[l-1]*rsqrt(deg[l-1]deg[l]);
    // gnn = relu(out + b_gcn). deg[0]=1; deg[v>=1] = 1 + (v < valid).
    if (act) {
        const bool hm = (l >= 1) && (l < valid);
        const float degl  = 1.f + ((l >= 1 && l < valid) ? 1.f : 0.f);
        const float deglm = 1.f + ((l - 1 >= 1 && (l - 1) < valid) ? 1.f : 0.f);
        const float invd  = 1.f / degl;                    // deg in {1,2}: exact
        const float invn  = hm ? rsqrtf(deglm * degl) : 0.f;
        const int lm = hm ? (l - 1) : l;                   // safe LDS index when !hm
        const float4 bg4 = ((const float4*)b_gcn)[dg];
        float m;
        m = hm ? xwT[4 * dg + 0][lm] * invn : 0.f;
        o.x = fmaxf(fmaf(o.x, invd, m) + bg4.x, 0.f);
        m = hm ? xwT[4 * dg + 1][lm] * invn : 0.f;
        o.y = fmaxf(fmaf(o.y, invd, m) + bg4.y, 0.f);
        m = hm ? xwT[4 * dg + 2][lm] * invn : 0.f;
        o.z = fmaxf(fmaf(o.z, invd, m) + bg4.z, 0.f);
        m = hm ? xwT[4 * dg + 3][lm] * invn : 0.f;
        o.w = fmaxf(fmaf(o.w, invd, m) + bg4.w, 0.f);
    }
    __syncthreads();   // all xwT reads done before overwrite (WAR)

    if (act) {
        xwT[4 * dg + 0][l] = o.x;
        xwT[4 * dg + 1][l] = o.y;
        xwT[4 * dg + 2][l] = o.z;
        xwT[4 * dg + 3][l] = o.w;
    }
    __syncthreads();

    // global_mean_pool over L=100 (32 lanes, reads (5t+j)%32: conflict-free)
    if (t < 32) {
        float s = 0.f;
        for (int j = 0; j < 100; ++j) s += xwT[t][j];
        pooled[t] = s * 0.01f;
    }
    __syncthreads();

    if (t < 32) {
        float s = b_out[t];
        #pragma unroll 8
        for (int k = 0; k < 32; ++k) s = fmaf(pooled[k], Wol[k * 32 + t], s);
        out[(size_t)b * 32 + t] = s;                       // src_emb
    } else if (t < 64) {
        const int d = t - 32;
        const __half* fr = feat + (size_t)dst_ids[b] * 32; // broadcast reads
        float s = b_out[d];
        #pragma unroll 8
        for (int k = 0; k < 32; ++k)
            s = fmaf(__half2float(fr[k]), Wol[k * 32 + d], s);
        out[(size_t)B * 32 + (size_t)b * 32 + d] = s;      // dst_emb
    }
}

// ---------------------------------------------------------------------------
extern "C" void kernel_launch(void* const* d_in, const int* in_sizes, int n_in,
                              void* d_out, int out_size, void* d_ws, size_t ws_size,
                              hipStream_t stream)
{
    const float* X      = (const float*)d_in[0];   // [N,128]
    const int*   rnodes = (const int*)  d_in[1];   // [P,100]
    const int*   ridx   = (const int*)  d_in[2];   // [B,5]
    /* d_in[3] src_node_ids: unused by reference */
    const int*   dst    = (const int*)  d_in[4];   // [B]
    /* d_in[5] node_interact_times: unused */
    const float* Wf  = (const float*)d_in[6];
    const float* bf  = (const float*)d_in[7];
    const float* wst = (const float*)d_in[8];
    const float* bst = (const float*)d_in[9];
    const float* lg  = (const float*)d_in[10];
    const float* lb  = (const float*)d_in[11];
    const float* Wg  = (const float*)d_in[12];
    const float* bg  = (const float*)d_in[13];
    const float* Wo  = (const float*)d_in[14];
    const float* bo  = (const float*)d_in[15];

    const int N = in_sizes[0] / 128;   // 100000
    const int B = in_sizes[4];         // 1024

    // workspace: feat_all [N,32] fp16 (6.4MB) | skill [N] i32 (16B-aligned)
    __half* feat = (__half*)d_ws;
    size_t feat_bytes = (((size_t)N * 32 * sizeof(__half)) + 15) & ~(size_t)15;
    int* skill = (int*)((char*)d_ws + feat_bytes);
    float* out = (float*)d_out;

    k_feat<<<(N * 8 + 255) / 256, 256, 0, stream>>>(X, Wf, bf, feat, skill, N);
    k_fused<<<B, 1024, 0, stream>>>(feat, skill, rnodes, ridx, dst,
                                    wst, bst, lg, lb, Wg, bg, Wo, bo, out, B);
}